// Round 1
// baseline (1739.370 us; speedup 1.0000x reference)
//
#include <hip/hip_runtime.h>
#include <cstdint>
#include <cstddef>

#define HW 16384

// ---------------- layout transforms ----------------

__global__ void k_nchw_to_nhwc(const float* __restrict__ in, float* __restrict__ out,
                               int C) {
  int total = 2 * C * HW;
  for (int idx = blockIdx.x * blockDim.x + threadIdx.x; idx < total;
       idx += gridDim.x * blockDim.x) {
    int b = idx / (C * HW);
    int r = idx - b * C * HW;
    int c = r / HW;
    int p = r - c * HW;
    out[((size_t)b * HW + p) * C + c] = in[idx];
  }
}

// w: (O, C, 9) -> wT: (C*9, O)
__global__ void k_transpose_w(const float* __restrict__ w, float* __restrict__ wT,
                              int O, int C) {
  int total = O * C * 9;
  for (int idx = blockIdx.x * blockDim.x + threadIdx.x; idx < total;
       idx += gridDim.x * blockDim.x) {
    int o = idx / (C * 9);
    int r = idx - o * C * 9;  // c*9+k
    wT[(size_t)r * O + o] = w[idx];
  }
}

// ---------------- 3x3 conv producing offsets (18ch) + mask (9ch, 2*sigmoid) ----------------

template <int C>
__global__ __launch_bounds__(256)
void k_conv_offmask(const float* __restrict__ xn,          // (B,HW,C) NHWC
                    const float* __restrict__ ow, const float* __restrict__ ob,
                    const float* __restrict__ mw, const float* __restrict__ mb,
                    float* __restrict__ off,               // (B*HW, 18)
                    float* __restrict__ msk) {             // (B*HW, 9)
  int pix = blockIdx.x * 256 + threadIdx.x;  // 0..32767
  int b = pix >> 14;
  int p = pix & 16383;
  int y = p >> 7, x = p & 127;
  float acc[27];
#pragma unroll
  for (int i = 0; i < 18; i++) acc[i] = ob[i];
#pragma unroll
  for (int i = 0; i < 9; i++) acc[18 + i] = mb[i];
  const float* xb = xn + (size_t)b * HW * C;
  for (int c = 0; c < C; c++) {
    float xv[9];
#pragma unroll
    for (int t = 0; t < 9; t++) {
      int yy = y + t / 3 - 1, xx = x + t % 3 - 1;
      bool v = (yy >= 0) && (yy < 128) && (xx >= 0) && (xx < 128);
      xv[t] = v ? xb[(size_t)(yy * 128 + xx) * C + c] : 0.f;
    }
#pragma unroll
    for (int o = 0; o < 18; o++) {
      const float* wp = ow + (o * C + c) * 9;
#pragma unroll
      for (int t = 0; t < 9; t++) acc[o] += xv[t] * wp[t];
    }
#pragma unroll
    for (int o = 0; o < 9; o++) {
      const float* wp = mw + (o * C + c) * 9;
#pragma unroll
      for (int t = 0; t < 9; t++) acc[18 + o] += xv[t] * wp[t];
    }
  }
  float* op = off + (size_t)pix * 18;
#pragma unroll
  for (int i = 0; i < 18; i++) op[i] = acc[i];
  float* mp = msk + (size_t)pix * 9;
#pragma unroll
  for (int i = 0; i < 9; i++) mp[i] = 2.f / (1.f + expf(-acc[18 + i]));
}

// ---------------- deformable conv: bilinear sample into LDS, then einsum ----------------

template <int C, int O, int TP>
__global__ __launch_bounds__(256)
void k_deform(const float* __restrict__ src,  // (B,HW,C) NHWC
              const float* __restrict__ off,  // (B*HW,18)
              const float* __restrict__ msk,  // (B*HW,9)
              const float* __restrict__ wT,   // (C*9, O)
              float* __restrict__ out) {      // (B,HW,O) NHWC
  static_assert(256 % O == 0, "");
  constexpr int G = 256 / O;
  constexpr int PPT = TP / G;
  static_assert(TP % G == 0, "");
  __shared__ float val[TP][9][C];
  int tid = threadIdx.x;
  int lane = tid & 63, wid = tid >> 6;
  int pix0 = blockIdx.x * TP;  // 16384 % TP == 0, so tile stays in one batch
  int b = pix0 >> 14;
  const float* sb = src + (size_t)b * HW * C;

  for (int pair = wid; pair < TP * 9; pair += 4) {
    int p = pair / 9, k = pair - 9 * (pair / 9);
    int pg = (pix0 + p) & 16383;
    int y = pg >> 7, x = pg & 127;
    size_t obase = (size_t)(pix0 + p);
    float dy = off[obase * 18 + 2 * k];
    float dx = off[obase * 18 + 2 * k + 1];
    float m = msk[obase * 9 + k];
    float py = dy + (float)(k / 3) + (float)(y - 1);
    float px = dx + (float)(k % 3) + (float)(x - 1);
    float y0f = floorf(py), x0f = floorf(px);
    float ly = py - y0f, lx = px - x0f;
    int y0 = (int)y0f, x0 = (int)x0f;
    int y1 = y0 + 1, x1 = x0 + 1;
    float w00 = (1.f - ly) * (1.f - lx);
    float w01 = (1.f - ly) * lx;
    float w10 = ly * (1.f - lx);
    float w11 = ly * lx;
    if (!(y0 >= 0 && y0 < 128)) { w00 = 0.f; w01 = 0.f; }
    if (!(y1 >= 0 && y1 < 128)) { w10 = 0.f; w11 = 0.f; }
    if (!(x0 >= 0 && x0 < 128)) { w00 = 0.f; w10 = 0.f; }
    if (!(x1 >= 0 && x1 < 128)) { w01 = 0.f; w11 = 0.f; }
    int cy0 = min(max(y0, 0), 127), cy1 = min(max(y1, 0), 127);
    int cx0 = min(max(x0, 0), 127), cx1 = min(max(x1, 0), 127);
    const float* p00 = sb + (size_t)(cy0 * 128 + cx0) * C;
    const float* p01 = sb + (size_t)(cy0 * 128 + cx1) * C;
    const float* p10 = sb + (size_t)(cy1 * 128 + cx0) * C;
    const float* p11 = sb + (size_t)(cy1 * 128 + cx1) * C;
#pragma unroll
    for (int j = 0; j < C / 64; j++) {
      int c = j * 64 + lane;
      float v = w00 * p00[c] + w01 * p01[c] + w10 * p10[c] + w11 * p11[c];
      val[p][k][c] = v * m;
    }
  }
  __syncthreads();

  int o = tid % O;
  int g = tid / O;
  float acc[PPT];
#pragma unroll
  for (int i = 0; i < PPT; i++) acc[i] = 0.f;
  for (int c = 0; c < C; c++) {
#pragma unroll
    for (int k = 0; k < 9; k++) {
      float wv = wT[(size_t)(c * 9 + k) * O + o];
#pragma unroll
      for (int i = 0; i < PPT; i++) acc[i] += wv * val[g + G * i][k][c];
    }
  }
#pragma unroll
  for (int i = 0; i < PPT; i++) {
    out[(size_t)(pix0 + g + G * i) * O + o] = acc[i];
  }
}

// ---------------- channel-LayerNorm + exact GELU ----------------

template <int C, bool NCHW_OUT>
__global__ __launch_bounds__(256)
void k_ln_gelu(const float* __restrict__ src,  // (B,HW,C) NHWC
               const float* __restrict__ w, const float* __restrict__ bb,
               float* __restrict__ dst) {
  int pix = blockIdx.x * 256 + threadIdx.x;  // 0..32767
  const float* row = src + (size_t)pix * C;
  float sum = 0.f, sumsq = 0.f;
  for (int c = 0; c < C; c += 4) {
    float4 v = *reinterpret_cast<const float4*>(row + c);
    sum += v.x + v.y + v.z + v.w;
    sumsq += v.x * v.x + v.y * v.y + v.z * v.z + v.w * v.w;
  }
  float mean = sum * (1.f / C);
  float var = sumsq * (1.f / C) - mean * mean;
  float inv = 1.f / sqrtf(var + 1e-5f);
  int b = pix >> 14, p = pix & 16383;
  for (int c = 0; c < C; c++) {
    float xh = (row[c] - mean) * inv;
    float yv = w[c] * xh + bb[c];
    float gv = 0.5f * yv * (1.f + erff(yv * 0.70710678118654752f));
    if (NCHW_OUT)
      dst[((size_t)(b * C + c) << 14) + p] = gv;
    else
      dst[(size_t)pix * C + c] = gv;
  }
}

// ---------------- launch ----------------

extern "C" void kernel_launch(void* const* d_in, const int* in_sizes, int n_in,
                              void* d_out, int out_size, void* d_ws, size_t ws_size,
                              hipStream_t stream) {
  const float* x      = (const float*)d_in[0];
  const float* off1_w = (const float*)d_in[1];
  const float* off1_b = (const float*)d_in[2];
  const float* mod1_w = (const float*)d_in[3];
  const float* mod1_b = (const float*)d_in[4];
  const float* reg1_w = (const float*)d_in[5];
  const float* ln1_w  = (const float*)d_in[6];
  const float* ln1_b  = (const float*)d_in[7];
  const float* off2_w = (const float*)d_in[8];
  const float* off2_b = (const float*)d_in[9];
  const float* mod2_w = (const float*)d_in[10];
  const float* mod2_b = (const float*)d_in[11];
  const float* reg2_w = (const float*)d_in[12];
  const float* ln2_w  = (const float*)d_in[13];
  const float* ln2_b  = (const float*)d_in[14];
  float* out = (float*)d_out;

  float* ws = (float*)d_ws;
  float* x_nhwc = ws; ws += 2097152;   // (2,HW,64)
  float* off1   = ws; ws += 589824;    // (2*HW,18)
  float* mask1  = ws; ws += 294912;    // (2*HW,9)
  float* wT1    = ws; ws += 147456;    // (64*9,256)
  float* wT2    = ws; ws += 147456;    // (256*9,64)
  float* h1     = ws; ws += 8388608;   // (2,HW,256) ; LN1 applied in-place
  float* off2   = ws; ws += 589824;
  float* mask2  = ws; ws += 294912;
  float* h2     = ws; ws += 2097152;   // (2,HW,64)

  hipLaunchKernelGGL(k_nchw_to_nhwc, dim3(2048), dim3(256), 0, stream, x, x_nhwc, 64);
  hipLaunchKernelGGL(k_transpose_w, dim3(64), dim3(256), 0, stream, reg1_w, wT1, 256, 64);
  hipLaunchKernelGGL(k_transpose_w, dim3(64), dim3(256), 0, stream, reg2_w, wT2, 64, 256);

  hipLaunchKernelGGL((k_conv_offmask<64>), dim3(128), dim3(256), 0, stream,
                     x_nhwc, off1_w, off1_b, mod1_w, mod1_b, off1, mask1);
  hipLaunchKernelGGL((k_deform<64, 256, 8>), dim3(4096), dim3(256), 0, stream,
                     x_nhwc, off1, mask1, wT1, h1);
  hipLaunchKernelGGL((k_ln_gelu<256, false>), dim3(128), dim3(256), 0, stream,
                     h1, ln1_w, ln1_b, h1);

  hipLaunchKernelGGL((k_conv_offmask<256>), dim3(128), dim3(256), 0, stream,
                     h1, off2_w, off2_b, mod2_w, mod2_b, off2, mask2);
  hipLaunchKernelGGL((k_deform<256, 64, 4>), dim3(8192), dim3(256), 0, stream,
                     h1, off2, mask2, wT2, h2);
  hipLaunchKernelGGL((k_ln_gelu<64, true>), dim3(128), dim3(256), 0, stream,
                     h2, ln2_w, ln2_b, out);
}

// Round 3
// 298.194 us; speedup vs baseline: 5.8330x; 5.8330x over previous
//
#include <hip/hip_runtime.h>
#include <hip/hip_bf16.h>
#include <cstdint>
#include <cstddef>

typedef __attribute__((ext_vector_type(8))) _Float16 f16x8;
typedef __attribute__((ext_vector_type(4))) float f32x4;

__device__ inline uint32_t packh(float a, float b) {
  union { _Float16 h[2]; uint32_t u; } v;
  v.h[0] = (_Float16)a; v.h[1] = (_Float16)b;
  return v.u;
}
__device__ inline float hlo(uint32_t u) {
  union { uint32_t u; _Float16 h[2]; } v; v.u = u; return (float)v.h[0];
}
__device__ inline float hhi(uint32_t u) {
  union { uint32_t u; _Float16 h[2]; } v; v.u = u; return (float)v.h[1];
}
__device__ inline float gelu(float v) {
  return 0.5f * v * (1.f + erff(v * 0.70710678118654752f));
}

// ---------- prep: x fp32 NCHW -> fp16 swizzled NHWC (word key (p&7)<<2) ----------
__global__ __launch_bounds__(256)
void k_prep_x(const float* __restrict__ x, uint32_t* __restrict__ xs) {
  __shared__ float t[64][65];
  int tid = threadIdx.x;
  int p0 = blockIdx.x * 64;
  int b = p0 >> 14, pl0 = p0 & 16383;
  for (int i = tid; i < 64 * 64; i += 256) {
    int c = i >> 6, p = i & 63;
    t[c][p] = x[((size_t)(b * 64 + c) << 14) + pl0 + p];
  }
  __syncthreads();
  for (int s0 = tid; s0 < 64 * 32; s0 += 256) {
    int p = s0 >> 5, cp = s0 & 31;
    int c = 2 * cp;
    xs[(size_t)(p0 + p) * 32 + (cp ^ ((p & 7) << 2))] = packh(t[c][p], t[c + 1][p]);
  }
}

// ---------- prep: deform weight (O,C,3,3) -> (9, O, C/2) fp16 pairs, swizzled by o ----------
template <int O, int C>
__global__ void k_prep_wB(const float* __restrict__ wsrc, uint32_t* __restrict__ dst) {
  constexpr int CW = C / 2;
  int total = 9 * O * CW;
  for (int i = blockIdx.x * 256 + threadIdx.x; i < total; i += gridDim.x * 256) {
    int k = i / (O * CW);
    int r = i - k * (O * CW);
    int o = r / CW, cp = r - o * CW;
    int c0 = (2 * cp) ^ ((o & 7) << 3);
    float a = wsrc[((size_t)o * C + c0) * 9 + k];
    float bv = wsrc[((size_t)o * C + c0 + 1) * 9 + k];
    dst[i] = packh(a, bv);
  }
}

// ---------- prep: conv weights (18+9 -> 32 padded) -> (9, 32, C/2) swizzled ----------
template <int C>
__global__ void k_prep_wC(const float* __restrict__ ow, const float* __restrict__ mw,
                          uint32_t* __restrict__ dst) {
  constexpr int CW = C / 2;
  int total = 9 * 32 * CW;
  for (int i = blockIdx.x * 256 + threadIdx.x; i < total; i += gridDim.x * 256) {
    int k = i / (32 * CW);
    int r = i - k * (32 * CW);
    int o = r / CW, cp = r - o * CW;
    int c0 = (2 * cp) ^ ((o & 7) << 3);
    float a = 0.f, bv = 0.f;
    if (o < 18) {
      a  = ow[((size_t)o * C + c0) * 9 + k];
      bv = ow[((size_t)o * C + c0 + 1) * 9 + k];
    } else if (o < 27) {
      a  = mw[((size_t)(o - 18) * C + c0) * 9 + k];
      bv = mw[((size_t)(o - 18) * C + c0 + 1) * 9 + k];
    }
    dst[i] = packh(a, bv);
  }
}

// ---------- MFMA 3x3 conv: offsets(18) + mask-logits(9) in one N=32 tile ----------
template <int C>
__global__ __launch_bounds__(256)
void k_conv(const uint32_t* __restrict__ src, const uint32_t* __restrict__ wC,
            const float* __restrict__ ob, const float* __restrict__ mb,
            float* __restrict__ off, float* __restrict__ msk) {
  constexpr int CW = C / 2;
  __shared__ union {
    struct { uint32_t A[64 * CW]; uint32_t B[32 * CW]; } s;
    float Cst[64 * 33];
  } u;
  int tid = threadIdx.x;
  int lane = tid & 63, w = tid >> 6;
  int p0 = blockIdx.x * 64;
  int b = p0 >> 14;
  int pl0 = p0 & 16383;
  int y = pl0 >> 7, x0 = pl0 & 127;

  f32x4 acc[2] = {{0.f, 0.f, 0.f, 0.f}, {0.f, 0.f, 0.f, 0.f}};

  for (int k = 0; k < 9; ++k) {
    int dy = k / 3 - 1, dx = k % 3 - 1;
    int yy = y + dy;
    if ((unsigned)yy >= 128u) continue;  // uniform over block
    __syncthreads();
    const uint32_t* bs = wC + (size_t)k * 32 * CW;
    for (int i = tid; i < 32 * CW; i += 256) u.s.B[i] = bs[i];
    int q0 = (b << 14) + yy * 128 + x0 + dx;
    for (int s0 = tid; s0 < 64 * CW; s0 += 256) {
      int i = s0 / CW, cp = s0 - (s0 / CW) * CW;
      int xx = x0 + dx + i;
      bool valid = (unsigned)xx < 128u;
      int q = valid ? (q0 + i) : (b << 14);
      uint32_t v = src[(size_t)q * CW + (cp ^ ((q & 7) << 2))];
      u.s.A[i * CW + (cp ^ ((i & 7) << 2))] = valid ? v : 0u;
    }
    __syncthreads();
#pragma unroll
    for (int kk = 0; kk < C / 32; ++kk) {
      int ce = kk * 32 + (lane >> 4) * 8;
      int row = w * 16 + (lane & 15);
      f16x8 af = *(const f16x8*)((const char*)u.s.A + row * (C * 2) +
                                 ((ce ^ ((row & 7) << 3)) * 2));
#pragma unroll
      for (int nr = 0; nr < 2; ++nr) {
        int col = nr * 16 + (lane & 15);
        f16x8 bfr = *(const f16x8*)((const char*)u.s.B + col * (C * 2) +
                                    ((ce ^ ((col & 7) << 3)) * 2));
        acc[nr] = __builtin_amdgcn_mfma_f32_16x16x32_f16(af, bfr, acc[nr], 0, 0, 0);
      }
    }
  }
  __syncthreads();
#pragma unroll
  for (int nr = 0; nr < 2; ++nr) {
    int col = nr * 16 + (lane & 15);
    float bias = (col < 18) ? ob[col] : ((col < 27) ? mb[col - 18] : 0.f);
#pragma unroll
    for (int r = 0; r < 4; ++r) {
      int p = w * 16 + ((lane >> 4) << 2) + r;
      u.Cst[p * 33 + col] = acc[nr][r] + bias;
    }
  }
  __syncthreads();
  for (int i = tid; i < 64 * 18; i += 256) {
    int p = i / 18, o = i - 18 * p;
    off[(size_t)p0 * 18 + i] = u.Cst[p * 33 + o];
  }
  for (int i = tid; i < 64 * 9; i += 256) {
    int p = i / 9, o = i - 9 * p;
    float z = u.Cst[p * 33 + 18 + o];
    msk[(size_t)p0 * 9 + i] = 2.f / (1.f + expf(-z));
  }
}

// ---------- MFMA deformable conv + fused channel-LN + GELU ----------
template <int C, int O, bool FINAL>
__global__ __launch_bounds__(256)
void k_deform(const uint32_t* __restrict__ src,   // (32768, C/2) fp16 pairs, swizzled
              const float* __restrict__ off, const float* __restrict__ msk,
              const uint32_t* __restrict__ wB,    // (9, O, C/2) swizzled
              const float* __restrict__ lnw, const float* __restrict__ lnb,
              void* __restrict__ outp) {
  constexpr int NWN = (O > 64) ? 4 : 2;
  constexpr int NWM = 4 / NWN;
  constexpr int WM = 64 / NWM;
  constexpr int WN = O / NWN;
  constexpr int MR = WM / 16, NR = WN / 16;
  constexpr int CW = C / 2;

  __shared__ union {
    struct {
      uint32_t A[64 * CW];
      uint32_t B[O * CW];
      float4 pw[576];
      uint2  pq[576];
    } s;
    float Cst[64 * O];
  } u;
  __shared__ float smean[64], sinv[64];

  int tid = threadIdx.x;
  int lane = tid & 63, w = tid >> 6;
  int wm = w / NWN, wn = w - NWN * (w / NWN);
  int p0 = blockIdx.x * 64;
  int b = p0 >> 14;

  // phase A: bilinear weights (x mask) + clamped corner pixel indices per (p,k)
  for (int e = tid; e < 576; e += 256) {
    int p = e / 9, k = e - 9 * (e / 9);
    int pix = p0 + p;
    int pl = pix & 16383;
    int yc = pl >> 7, xc = pl & 127;
    float dy = off[(size_t)pix * 18 + 2 * k];
    float dx = off[(size_t)pix * 18 + 2 * k + 1];
    float m = msk[(size_t)pix * 9 + k];
    float py = dy + (float)(k / 3) + (float)(yc - 1);
    float px = dx + (float)(k - 3 * (k / 3)) + (float)(xc - 1);
    float y0f = floorf(py), x0f = floorf(px);
    float ly = py - y0f, lx = px - x0f;
    int y0i = (int)y0f, x0i = (int)x0f;
    int y1i = y0i + 1, x1i = x0i + 1;
    float w00 = (1.f - ly) * (1.f - lx), w01 = (1.f - ly) * lx;
    float w10 = ly * (1.f - lx), w11 = ly * lx;
    if (!(y0i >= 0 && y0i < 128)) { w00 = 0.f; w01 = 0.f; }
    if (!(y1i >= 0 && y1i < 128)) { w10 = 0.f; w11 = 0.f; }
    if (!(x0i >= 0 && x0i < 128)) { w00 = 0.f; w10 = 0.f; }
    if (!(x1i >= 0 && x1i < 128)) { w01 = 0.f; w11 = 0.f; }
    int cy0 = min(max(y0i, 0), 127), cy1 = min(max(y1i, 0), 127);
    int cx0 = min(max(x0i, 0), 127), cx1 = min(max(x1i, 0), 127);
    int base = b << 14;
    uint32_t q00 = base + cy0 * 128 + cx0, q01 = base + cy0 * 128 + cx1;
    uint32_t q10 = base + cy1 * 128 + cx0, q11 = base + cy1 * 128 + cx1;
    u.s.pw[e] = make_float4(w00 * m, w01 * m, w10 * m, w11 * m);
    u.s.pq[e] = make_uint2(q00 | (q01 << 16), q10 | (q11 << 16));
  }

  f32x4 acc[MR][NR];
#pragma unroll
  for (int mr = 0; mr < MR; ++mr)
#pragma unroll
    for (int nr = 0; nr < NR; ++nr) acc[mr][nr] = {0.f, 0.f, 0.f, 0.f};

  for (int k = 0; k < 9; ++k) {
    __syncthreads();
    const uint32_t* bs = wB + (size_t)k * O * CW;
    for (int i = tid; i < O * CW; i += 256) u.s.B[i] = bs[i];
    for (int s0 = tid; s0 < 64 * CW; s0 += 256) {
      int p = s0 / CW, cp = s0 - (s0 / CW) * CW;
      float4 wt = u.s.pw[p * 9 + k];
      uint2 qq = u.s.pq[p * 9 + k];
      int q00 = qq.x & 0xffff, q01 = qq.x >> 16;
      int q10 = qq.y & 0xffff, q11 = qq.y >> 16;
      uint32_t v00 = src[(size_t)q00 * CW + (cp ^ ((q00 & 7) << 2))];
      uint32_t v01 = src[(size_t)q01 * CW + (cp ^ ((q01 & 7) << 2))];
      uint32_t v10 = src[(size_t)q10 * CW + (cp ^ ((q10 & 7) << 2))];
      uint32_t v11 = src[(size_t)q11 * CW + (cp ^ ((q11 & 7) << 2))];
      float r0 = hlo(v00) * wt.x + hlo(v01) * wt.y + hlo(v10) * wt.z + hlo(v11) * wt.w;
      float r1 = hhi(v00) * wt.x + hhi(v01) * wt.y + hhi(v10) * wt.z + hhi(v11) * wt.w;
      u.s.A[p * CW + (cp ^ ((p & 7) << 2))] = packh(r0, r1);
    }
    __syncthreads();
#pragma unroll
    for (int kk = 0; kk < C / 32; ++kk) {
      int ce = kk * 32 + (lane >> 4) * 8;
      f16x8 af[MR], bfr[NR];
#pragma unroll
      for (int mr = 0; mr < MR; ++mr) {
        int row = wm * WM + mr * 16 + (lane & 15);
        af[mr] = *(const f16x8*)((const char*)u.s.A + row * (C * 2) +
                                 ((ce ^ ((row & 7) << 3)) * 2));
      }
#pragma unroll
      for (int nr = 0; nr < NR; ++nr) {
        int col = wn * WN + nr * 16 + (lane & 15);
        bfr[nr] = *(const f16x8*)((const char*)u.s.B + col * (C * 2) +
                                  ((ce ^ ((col & 7) << 3)) * 2));
      }
#pragma unroll
      for (int mr = 0; mr < MR; ++mr)
#pragma unroll
        for (int nr = 0; nr < NR; ++nr)
          acc[mr][nr] = __builtin_amdgcn_mfma_f32_16x16x32_f16(af[mr], bfr[nr],
                                                               acc[mr][nr], 0, 0, 0);
    }
  }

  // epilogue: regs -> Cst (f32, word-swizzled), stats, LN+GELU, store
  __syncthreads();
#pragma unroll
  for (int mr = 0; mr < MR; ++mr) {
    int prow = wm * WM + mr * 16 + ((lane >> 4) << 2);
#pragma unroll
    for (int nr = 0; nr < NR; ++nr) {
      int col = wn * WN + nr * 16 + (lane & 15);
#pragma unroll
      for (int r = 0; r < 4; ++r) {
        int p = prow + r;
        u.Cst[p * O + (col ^ ((p & 15) << 2))] = acc[mr][nr][r];
      }
    }
  }
  __syncthreads();
  {
    int p = tid >> 2, sub = tid & 3;
    float s = 0.f, s2 = 0.f;
#pragma unroll
    for (int j = 0; j < O / 16; ++j) {
      int o0 = (sub * (O / 4) + j * 4) ^ ((p & 15) << 2);
      float4 v = *(const float4*)&u.Cst[p * O + o0];
      s += v.x + v.y + v.z + v.w;
      s2 += v.x * v.x + v.y * v.y + v.z * v.z + v.w * v.w;
    }
    s += __shfl_xor(s, 1); s += __shfl_xor(s, 2);
    s2 += __shfl_xor(s2, 1); s2 += __shfl_xor(s2, 2);
    if (sub == 0) {
      float mean = s * (1.f / O);
      float var = s2 * (1.f / O) - mean * mean;
      smean[p] = mean;
      sinv[p] = rsqrtf(var + 1e-5f);
    }
  }
  __syncthreads();
  if (!FINAL) {
    uint32_t* dst = (uint32_t*)outp;
    constexpr int OW = O / 2;
    for (int s0 = tid; s0 < 64 * OW; s0 += 256) {
      int p = s0 / OW, op = s0 - (s0 / OW) * OW;
      int o = 2 * op;
      int ow = o ^ ((p & 15) << 2);
      float c0 = u.Cst[p * O + ow];
      float c1 = u.Cst[p * O + ow + 1];
      float m = smean[p], iv = sinv[p];
      float g0 = gelu((c0 - m) * iv * lnw[o] + lnb[o]);
      float g1 = gelu((c1 - m) * iv * lnw[o + 1] + lnb[o + 1]);
      dst[(size_t)(p0 + p) * OW + (op ^ ((p & 7) << 2))] = packh(g0, g1);
    }
  } else {
    float* dst = (float*)outp;
    int pl0 = p0 & 16383;
    for (int s0 = tid; s0 < 64 * O; s0 += 256) {
      int o = s0 >> 6, p = s0 & 63;
      float c = u.Cst[p * O + (o ^ ((p & 15) << 2))];
      float m = smean[p], iv = sinv[p];
      float g = gelu((c - m) * iv * lnw[o] + lnb[o]);
      dst[((size_t)(b * 64 + o) << 14) + pl0 + p] = g;
    }
  }
}

// ---------------- launch ----------------
extern "C" void kernel_launch(void* const* d_in, const int* in_sizes, int n_in,
                              void* d_out, int out_size, void* d_ws, size_t ws_size,
                              hipStream_t stream) {
  const float* x      = (const float*)d_in[0];
  const float* off1_w = (const float*)d_in[1];
  const float* off1_b = (const float*)d_in[2];
  const float* mod1_w = (const float*)d_in[3];
  const float* mod1_b = (const float*)d_in[4];
  const float* reg1_w = (const float*)d_in[5];
  const float* ln1_w  = (const float*)d_in[6];
  const float* ln1_b  = (const float*)d_in[7];
  const float* off2_w = (const float*)d_in[8];
  const float* off2_b = (const float*)d_in[9];
  const float* mod2_w = (const float*)d_in[10];
  const float* mod2_b = (const float*)d_in[11];
  const float* reg2_w = (const float*)d_in[12];
  const float* ln2_w  = (const float*)d_in[13];
  const float* ln2_b  = (const float*)d_in[14];
  float* out = (float*)d_out;

  uint32_t* ws = (uint32_t*)d_ws;
  uint32_t* xs  = ws; ws += 32768 * 32;    // x fp16 swz NHWC
  uint32_t* h1s = ws; ws += 32768 * 128;   // h1 fp16 swz NHWC
  float* off1 = (float*)ws; ws += 32768 * 18;
  float* msk1 = (float*)ws; ws += 32768 * 9;
  float* off2 = (float*)ws; ws += 32768 * 18;
  float* msk2 = (float*)ws; ws += 32768 * 9;
  uint32_t* wB1 = ws; ws += 9 * 256 * 32;
  uint32_t* wB2 = ws; ws += 9 * 64 * 128;
  uint32_t* wC1 = ws; ws += 9 * 32 * 32;
  uint32_t* wC2 = ws; ws += 9 * 32 * 128;

  hipLaunchKernelGGL(k_prep_x, dim3(512), dim3(256), 0, stream, x, xs);
  hipLaunchKernelGGL((k_prep_wB<256, 64>), dim3(288), dim3(256), 0, stream, reg1_w, wB1);
  hipLaunchKernelGGL((k_prep_wB<64, 256>), dim3(288), dim3(256), 0, stream, reg2_w, wB2);
  hipLaunchKernelGGL((k_prep_wC<64>),  dim3(36),  dim3(256), 0, stream, off1_w, mod1_w, wC1);
  hipLaunchKernelGGL((k_prep_wC<256>), dim3(144), dim3(256), 0, stream, off2_w, mod2_w, wC2);

  hipLaunchKernelGGL((k_conv<64>), dim3(512), dim3(256), 0, stream,
                     xs, wC1, off1_b, mod1_b, off1, msk1);
  hipLaunchKernelGGL((k_deform<64, 256, false>), dim3(512), dim3(256), 0, stream,
                     xs, off1, msk1, wB1, ln1_w, ln1_b, (void*)h1s);
  hipLaunchKernelGGL((k_conv<256>), dim3(512), dim3(256), 0, stream,
                     h1s, wC2, off2_b, mod2_b, off2, msk2);
  hipLaunchKernelGGL((k_deform<256, 64, true>), dim3(512), dim3(256), 0, stream,
                     h1s, off2, msk2, wB2, ln2_w, ln2_b, (void*)out);
}